// Round 7
// baseline (654.870 us; speedup 1.0000x reference)
//
#include <hip/hip_runtime.h>
#include <cstdint>
#include <cstddef>

// ---------------- types ----------------
typedef __bf16 bf16;
typedef __bf16 bf16x4 __attribute__((ext_vector_type(4)));
typedef __bf16 bf16x8 __attribute__((ext_vector_type(8)));
typedef _Float16 f16;
typedef _Float16 f16x2 __attribute__((ext_vector_type(2)));
typedef _Float16 f16x4 __attribute__((ext_vector_type(4)));
typedef _Float16 f16x8 __attribute__((ext_vector_type(8)));
typedef float  f32x4  __attribute__((ext_vector_type(4)));
typedef float  f32x16 __attribute__((ext_vector_type(16)));
typedef int    i32x4  __attribute__((ext_vector_type(4)));
typedef int    i32x8  __attribute__((ext_vector_type(8)));
typedef unsigned char u8;

#define B_   16
#define N_   1024
#define C_   768
#define H_   12
#define HD_  64
#define M_   (B_*N_)      // 16384 rows
#define MLP_ 3072
#define QKVN 2304         // 3*C
#define WSCALE 64.0f      // weights cast to fp8 at x64 (0.02-scale weights are subnormal in e4m3)
#define WINV  (1.0f/64.0f)
#define CEXP_ 0.18033688f // 0.125 * log2(e) — folded into Q at the qkv-GEMM epilogue

__device__ __forceinline__ void gll16(const void* g, void* l) {
  __builtin_amdgcn_global_load_lds((const __attribute__((address_space(1))) void*)g,
                                   (__attribute__((address_space(3))) void*)l,
                                   16, 0, 0);
}

template <int N>
__device__ __forceinline__ void wait_vm() {
  if constexpr (N == 0)      asm volatile("s_waitcnt vmcnt(0)" ::: "memory");
  else if constexpr (N == 3) asm volatile("s_waitcnt vmcnt(3)" ::: "memory");
  else                       asm volatile("s_waitcnt vmcnt(4)" ::: "memory");
}

// native v_exp_f32 / v_rcp_f32 — libm forms lower to slow OCML sequences
__device__ __forceinline__ float fast_exp2(float x) { return __builtin_amdgcn_exp2f(x); }
__device__ __forceinline__ float fast_rcp(float x)  { return __builtin_amdgcn_rcpf(x); }

// packed f32x2 -> f16x2 (v_cvt_pkrtz_f16_f32); builtin returns __fp16 vector on
// this ROCm -> bit_cast to our _Float16 vector type
__device__ __forceinline__ f16x2 cvt_pk_f16(float a, float b) {
  return __builtin_bit_cast(f16x2, __builtin_amdgcn_cvt_pkrtz(a, b));
}

// fp8 e4m3 (OCP on gfx950) converts via HW packed cvt
__device__ __forceinline__ u8 to_fp8(float a) {
  return (u8)(__builtin_amdgcn_cvt_pk_fp8_f32(a, a, 0, false) & 0xff);
}
__device__ __forceinline__ int to_fp8x4(float v0, float v1, float v2, float v3) {
  int p = __builtin_amdgcn_cvt_pk_fp8_f32(v0, v1, 0, false);
  p = __builtin_amdgcn_cvt_pk_fp8_f32(v2, v3, p, true);
  return p;  // bytes [v0,v1,v2,v3]
}

// ---------------- fused prep: 4 weight transposes + LN1, one launch ----------------
// transpose tiles: qkv 72x24=1728 | proj 24x24=576 | fc1 96x24=2304 | fc2 24x96=2304
#define T_QKV  1728
#define T_PROJ 2304   // cumulative
#define T_FC1  4608
#define T_FC2  6912
#define T_ALL  6912

__device__ __forceinline__ void tc_tile(const float* __restrict__ w, u8* __restrict__ wt,
                                        int K, int N, int t, int tid) {
  __shared__ float tile[32][33];
  int tiles_n = N >> 5;
  int n0 = (t % tiles_n) * 32, k0 = (t / tiles_n) * 32;
  int tx = tid & 31, ty = tid >> 5;   // (32,8)
  #pragma unroll
  for (int i = 0; i < 32; i += 8)
    tile[ty + i][tx] = w[(size_t)(k0 + ty + i) * N + n0 + tx];
  __syncthreads();
  #pragma unroll
  for (int i = 0; i < 32; i += 8)
    wt[(size_t)(n0 + ty + i) * K + k0 + tx] = to_fp8(tile[tx][ty + i] * WSCALE);
}

__global__ __launch_bounds__(256)
void prep_kernel(const float* __restrict__ x,
                 const float* __restrict__ w_qkv, const float* __restrict__ w_proj,
                 const float* __restrict__ w_fc1, const float* __restrict__ w_fc2,
                 const float* __restrict__ g, const float* __restrict__ bta,
                 u8* __restrict__ wqkvT, u8* __restrict__ wprojT,
                 u8* __restrict__ wfc1T, u8* __restrict__ wfc2T,
                 u8* __restrict__ y) {
  int bid = blockIdx.x, tid = threadIdx.x;
  if (bid < T_ALL) {
    if (bid < T_QKV)       tc_tile(w_qkv,  wqkvT,  C_,   QKVN, bid,          tid);
    else if (bid < T_PROJ) tc_tile(w_proj, wprojT, C_,   C_,   bid - T_QKV,  tid);
    else if (bid < T_FC1)  tc_tile(w_fc1,  wfc1T,  C_,   MLP_, bid - T_PROJ, tid);
    else                   tc_tile(w_fc2,  wfc2T,  MLP_, C_,   bid - T_FC1,  tid);
    return;
  }
  // LayerNorm row
  int row = bid - T_ALL;
  const float* xr = x + (size_t)row * C_;
  float v0 = xr[tid], v1 = xr[tid + 256], v2 = xr[tid + 512];
  float s  = v0 + v1 + v2;
  float sq = v0 * v0 + v1 * v1 + v2 * v2;
  #pragma unroll
  for (int off = 32; off > 0; off >>= 1) {
    s  += __shfl_xor(s,  off);
    sq += __shfl_xor(sq, off);
  }
  __shared__ float red[8];
  int wave = tid >> 6, lane = tid & 63;
  if (lane == 0) { red[wave] = s; red[4 + wave] = sq; }
  __syncthreads();
  s  = red[0] + red[1] + red[2] + red[3];
  sq = red[4] + red[5] + red[6] + red[7];
  float mean = s * (1.0f / C_);
  float var  = sq * (1.0f / C_) - mean * mean;
  float rstd = rsqrtf(var + 1e-5f);
  u8* yr = y + (size_t)row * C_;
  yr[tid]       = to_fp8((v0 - mean) * rstd * g[tid]       + bta[tid]);
  yr[tid + 256] = to_fp8((v1 - mean) * rstd * g[tid + 256] + bta[tid + 256]);
  yr[tid + 512] = to_fp8((v2 - mean) * rstd * g[tid + 512] + bta[tid + 512]);
}

// ---------------- LayerNorm (768) + cast to fp8 (LN2) ----------------
__global__ __launch_bounds__(256)
void ln_cast_kernel(const float* __restrict__ x, const float* __restrict__ g,
                    const float* __restrict__ bta, u8* __restrict__ y) {
  int row = blockIdx.x;
  int tid = threadIdx.x;
  const float* xr = x + (size_t)row * C_;
  float v0 = xr[tid], v1 = xr[tid + 256], v2 = xr[tid + 512];
  float s  = v0 + v1 + v2;
  float sq = v0 * v0 + v1 * v1 + v2 * v2;
  #pragma unroll
  for (int off = 32; off > 0; off >>= 1) {
    s  += __shfl_xor(s,  off);
    sq += __shfl_xor(sq, off);
  }
  __shared__ float red[8];
  int wave = tid >> 6, lane = tid & 63;
  if (lane == 0) { red[wave] = s; red[4 + wave] = sq; }
  __syncthreads();
  s  = red[0] + red[1] + red[2] + red[3];
  sq = red[4] + red[5] + red[6] + red[7];
  float mean = s * (1.0f / C_);
  float var  = sq * (1.0f / C_) - mean * mean;
  float rstd = rsqrtf(var + 1e-5f);
  u8* yr = y + (size_t)row * C_;
  yr[tid]       = to_fp8((v0 - mean) * rstd * g[tid]       + bta[tid]);
  yr[tid + 256] = to_fp8((v1 - mean) * rstd * g[tid + 256] + bta[tid + 256]);
  yr[tid + 512] = to_fp8((v2 - mean) * rstd * g[tid + 512] + bta[tid + 512]);
}

// ---------------- fp8 GEMM: C[M,N] = A[M,K] @ Bt[N,K]^T, fp32 acc, result x(1/64) ----------
// R12 pipeline: 256-row tile, 8 waves (512 thr), 3 LDS buffers, prefetch depth 2,
// counted vmcnt (never 0 in steady state) + raw s_barrier. MX-scaled 32x32x64
// f8f6f4 with unit e8m0 scales. EPI==0 folds CEXP into Q columns (col < 768).
// R13: EPI==0 additionally writes the V columns (col >= 1536) transposed to
// vt[bh][d][n] as f16 (packed f16x4 over 4 consecutive rows) — this replaces the
// separate transpose_v kernel and single-rounds f32->f16 (was bf16->f16 double).
template <int EPI, int BN_>
__global__ __launch_bounds__(512, 2)
void gemm_bt(const u8* __restrict__ A, const u8* __restrict__ Bt,
             void* __restrict__ outp, const float* __restrict__ bias,
             const float* __restrict__ ls, const float* __restrict__ resid,
             f16* __restrict__ vt_out,
             int M, int N, int K, int nb) {
  constexpr int BM = 256, BK = 64;
  constexpr int NJ  = BN_ / 128;     // 32-col blocks per wave (2 or 1)
  constexpr int NBL = BN_ / 128;     // B-staging loads per thread per tile
  constexpr int TL  = 2 + NBL;       // total loads per thread per tile (4 or 3)
  __shared__ __align__(16) u8 As[3][BM * BK];    // 3 x 16 KB
  __shared__ __align__(16) u8 Bs[3][BN_ * BK];   // 3 x 16/8 KB
  int tid  = threadIdx.x;
  int lane = tid & 63, wave = tid >> 6;
  int h32 = lane >> 5, r5 = lane & 31;
  int bid = blockIdx.x;
  int xcd = bid & 7, seq = bid >> 3;
  int mi = xcd + 8 * (seq / nb), ni = seq % nb;
  int m0 = mi * BM, n0 = ni * BN_;
  int wm = (wave >> 2) * 128, wn = (wave & 3) * (BN_ / 4);

  int iters = K >> 6;                 // K / BK
  int skew  = (ni * iters) / nb;      // < iters

  // staging source pointers, granule-swizzled at the global side
  const u8* ag[2]; const u8* bg[NBL];
  #pragma unroll
  for (int s = 0; s < 2; s++) {
    int u = tid + s * 512;
    int r = u >> 2, g = (u & 3) ^ ((r >> 1) & 3);
    ag[s] = A + (size_t)(m0 + r) * K + g * 16;
  }
  #pragma unroll
  for (int s = 0; s < NBL; s++) {
    int u = tid + s * 512;
    int r = u >> 2, g = (u & 3) ^ ((r >> 1) & 3);
    bg[s] = Bt + (size_t)(n0 + r) * K + g * 16;
  }
  // fragment-read swizzled granule offsets (bits 1..2 of LDS row == bits 1..2 of r5)
  int sw  = (r5 >> 1) & 3;
  int go0 = ((2 * h32 + 0) ^ sw) * 16;   // true k-chunk 32*h32 + [0,16)
  int go1 = ((2 * h32 + 1) ^ sw) * 16;   // true k-chunk 32*h32 + [16,32)

  f32x16 acc[4][NJ];
  #pragma unroll
  for (int i = 0; i < 4; i++)
    #pragma unroll
    for (int j = 0; j < NJ; j++)
      #pragma unroll
      for (int rg = 0; rg < 16; rg++) acc[i][j][rg] = 0.f;

  // prologue: issue tiles k(0)->buf0, k(1)->buf1; wait only for k(0)
  int k0 = skew;
  int k1 = (skew + 1 == iters) ? 0 : skew + 1;
  {
    int kn = k0 * BK;
    gll16(ag[0] + kn, &As[0][0] + tid * 16);
    gll16(ag[1] + kn, &As[0][0] + 8192 + tid * 16);
    gll16(bg[0] + kn, &Bs[0][0] + tid * 16);
    if constexpr (NBL == 2) gll16(bg[1] + kn, &Bs[0][0] + 8192 + tid * 16);
    kn = k1 * BK;
    gll16(ag[0] + kn, &As[1][0] + tid * 16);
    gll16(ag[1] + kn, &As[1][0] + 8192 + tid * 16);
    gll16(bg[0] + kn, &Bs[1][0] + tid * 16);
    if constexpr (NBL == 2) gll16(bg[1] + kn, &Bs[1][0] + 8192 + tid * 16);
  }
  wait_vm<TL>();
  __builtin_amdgcn_s_barrier();
  int kiss = (k1 + 1 == iters) ? 0 : k1 + 1;   // next tile index to issue

  int buf_c = 0;
  for (int t = 0; t < iters; t++) {
    if (t + 2 < iters) {   // issue tile t+2 into buf (t+2)%3 (free since barrier t-1)
      int bi = (buf_c == 0) ? 2 : buf_c - 1;
      int kn = kiss * BK;
      gll16(ag[0] + kn, &As[bi][0] + tid * 16);
      gll16(ag[1] + kn, &As[bi][0] + 8192 + tid * 16);
      gll16(bg[0] + kn, &Bs[bi][0] + tid * 16);
      if constexpr (NBL == 2) gll16(bg[1] + kn, &Bs[bi][0] + 8192 + tid * 16);
      kiss = (kiss + 1 == iters) ? 0 : kiss + 1;
    }
    // LDS -> reg fragments: one 32-byte (2x b128) read per 32-row frag, per operand
    i32x8 af[4], bfr[NJ];
    #pragma unroll
    for (int i = 0; i < 4; i++) {
      const u8* pa = &As[buf_c][0] + (wm + i * 32 + r5) * 64;
      i32x4 lo = *(const i32x4*)(pa + go0);
      i32x4 hi = *(const i32x4*)(pa + go1);
      af[i] = __builtin_shufflevector(lo, hi, 0, 1, 2, 3, 4, 5, 6, 7);
    }
    #pragma unroll
    for (int j = 0; j < NJ; j++) {
      const u8* pb = &Bs[buf_c][0] + (wn + j * 32 + r5) * 64;
      i32x4 lo = *(const i32x4*)(pb + go0);
      i32x4 hi = *(const i32x4*)(pb + go1);
      bfr[j] = __builtin_shufflevector(lo, hi, 0, 1, 2, 3, 4, 5, 6, 7);
    }
    // MX-scaled fp8 MFMA, scales = e8m0 0x7f = 2^0 (exact 1.0)
    __builtin_amdgcn_s_setprio(1);
    #pragma unroll
    for (int i = 0; i < 4; i++)
      #pragma unroll
      for (int j = 0; j < NJ; j++)
        acc[i][j] = __builtin_amdgcn_mfma_scale_f32_32x32x64_f8f6f4(
            af[i], bfr[j], acc[i][j], 0, 0, 0, 0x7f7f7f7f, 0, 0x7f7f7f7f);
    __builtin_amdgcn_s_setprio(0);
    if (t + 1 < iters) {
      if (t + 2 < iters) wait_vm<TL>();   // tile t+1 landed; t+2 stays in flight
      else               wait_vm<0>();    // tail drain
      __builtin_amdgcn_s_barrier();
    }
    buf_c = (buf_c == 2) ? 0 : buf_c + 1;
  }

  // epilogue: 32x32 C/D map — col = lane&31, row = (reg&3) + 8*(reg>>2) + 4*(lane>>5)
  #pragma unroll
  for (int i = 0; i < 4; i++) {
    int rowb = m0 + wm + i * 32 + h32 * 4;
    #pragma unroll
    for (int j = 0; j < NJ; j++) {
      int col = n0 + wn + j * 32 + r5;
      float bias_c = (EPI == 0) ? 0.f : bias[col];
      float ls_c   = (EPI == 1 || EPI == 3) ? ls[col] : 0.f;
      float gz_v = -2.45546696f * WINV;
      float gz_b = -2.45546696f * bias_c;
      if constexpr (EPI == 0) {
        float sc0 = (col < C_) ? (WINV * CEXP_) : WINV;
        bool isv = (n0 + wn + j * 32) >= 2 * C_;   // wave-uniform (32-col blocks)
        #pragma unroll
        for (int g = 0; g < 4; g++) {
          f16x4 vv;
          #pragma unroll
          for (int rr = 0; rr < 4; rr++) {
            float v = acc[i][j][4 * g + rr];
            int row = rowb + rr + 8 * g;
            ((bf16*)outp)[(size_t)row * N + col] = (bf16)(v * sc0);
            vv[rr] = (f16)(v * WINV);
          }
          if (isv) {   // fused V transpose: vt[bh][d][n], 4 consecutive n packed
            int row0 = rowb + 8 * g;
            int bb = row0 >> 10, nn = row0 & 1023;
            int hh = (col - 2 * C_) >> 6, dd = (col - 2 * C_) & 63;
            *(f16x4*)(vt_out + ((size_t)(bb * H_ + hh) * HD_ + dd) * N_ + nn) = vv;
          }
        }
      } else {
        #pragma unroll
        for (int rg = 0; rg < 16; rg++) {
          float v = acc[i][j][rg];
          int row = rowb + (rg & 3) + 8 * (rg >> 2);
          size_t idx = (size_t)row * N + col;
          if constexpr (EPI == 1) {
            float t = fmaf(v, WINV, bias_c);
            ((float*)outp)[idx] = fmaf(t, ls_c, resid[idx]);
          } else if constexpr (EPI == 2) {
            float t  = fmaf(v, WINV, bias_c);
            float zn = fmaf(v, gz_v, gz_b);
            float gv = t * fast_rcp(1.0f + fast_exp2(zn));   // t * sigmoid(1.702 t)
            ((u8*)outp)[idx] = to_fp8(gv);
          } else {
            float t = fmaf(v, WINV, bias_c);
            ((float*)outp)[idx] = fmaf(t, ls_c, resid[idx]);
          }
        }
      }
    }
  }
}

// ---------------- flash attention, S^T formulation ----------------
// R13: one block = 256 q rows (two 128-row q-tiles processed SEQUENTIALLY per KV
// tile, reusing transient softmax registers). Grid 768 = exactly 3 blocks/CU, all
// co-resident in a single scheduling round (was 1536 blocks -> rounds of 4 + 2
// with a poorly-overlapped tail). K/V staging per q-row halves. launch_bounds
// (256,3) caps VGPR at 170 so 3 blocks/CU is guaranteed.
// XCD remap: bh = (bid&7) + 8*(seq>>2) — the 4 q-blocks of one bh share an XCD.
// kv-loop skewed by 2*qt (order-invariant, disjoint warm tiles).
// R10: no-max softmax (scores bounded; shift-invariant; fp8 downstream).
// R11: PV via K=32 f16 MFMA with slot-consistent key permutation.
__global__ __launch_bounds__(256, 3)
void attn_kernel(const bf16* __restrict__ qkv, const f16* __restrict__ vt,
                 u8* __restrict__ o) {
  constexpr int KSTR = 72;    // K tile stride (64 + 8 pad), bf16
  constexpr int VSTR = 136;   // V^T tile stride (128 + 8 pad), f16
  __shared__ __align__(16) bf16 Ks[128 * KSTR];   // 18432 B
  __shared__ __align__(16) f16  Vs[HD_ * VSTR];   // 17408 B

  int tid = threadIdx.x, lane = tid & 63, wave = tid >> 6;
  int quad = lane >> 4, l16 = lane & 15;
  int bid = blockIdx.x;
  int xcd = bid & 7, seq = bid >> 3;
  int bh = xcd + 8 * (seq >> 2);
  int b = bh / H_, h = bh % H_;
  int qt = seq & 3;
  int q0 = qt * 256;

  bf16x8 qf[2][2][2];   // [qs][i][kk]
  #pragma unroll
  for (int qs = 0; qs < 2; qs++)
    #pragma unroll
    for (int i = 0; i < 2; i++)
      #pragma unroll
      for (int kk = 0; kk < 2; kk++)
        qf[qs][i][kk] = *(const bf16x8*)(qkv
            + (size_t)(b * N_ + q0 + qs * 128 + wave * 32 + i * 16 + l16) * QKVN
            + h * HD_ + kk * 32 + quad * 8);

  const f32x4 fz = {0.f, 0.f, 0.f, 0.f};
  f32x4 oacc[2][2][4];         // [qs][i][d] — O^T[d = quad*4+r][q = l16]
  float l_run[2][2];
  #pragma unroll
  for (int qs = 0; qs < 2; qs++)
    #pragma unroll
    for (int i = 0; i < 2; i++) {
      #pragma unroll
      for (int jd = 0; jd < 4; jd++) oacc[qs][i][jd] = fz;
      l_run[qs][i] = 0.f;
    }

  const bf16* kbase = qkv + (size_t)(b * N_) * QKVN + C_ + h * HD_;
  const f16*  vbase = vt + (size_t)bh * HD_ * N_;

  // per-thread staging coords
  int kr[4], kc[4], vr[4], vc[4];
  #pragma unroll
  for (int u = 0; u < 4; u++) {
    int L = tid + u * 256;
    kr[u] = L >> 3;  kc[u] = (L & 7) * 8;
    vr[u] = L >> 4;  vc[u] = (L & 15) * 8;
  }

  // prefetch first (skewed) tile into registers
  bf16x8 kreg[4]; f16x8 vreg[4];
  {
    int kv = (2 * qt) * 128;   // skew start
    #pragma unroll
    for (int u = 0; u < 4; u++) {
      kreg[u] = *(const bf16x8*)(kbase + (size_t)(kv + kr[u]) * QKVN + kc[u]);
      vreg[u] = *(const f16x8*)(vbase + (size_t)vr[u] * N_ + kv + vc[u]);
    }
  }

  for (int t = 0; t < 8; t++) {
    __syncthreads();   // prior compute done reading LDS
    #pragma unroll
    for (int u = 0; u < 4; u++) {
      *(bf16x8*)(Ks + kr[u] * KSTR + kc[u]) = kreg[u];
      *(f16x8*)(Vs + vr[u] * VSTR + vc[u])  = vreg[u];
    }
    __syncthreads();

    // issue next (skewed) tile's loads; they complete during compute below
    if (t + 1 < 8) {
      int kv = ((t + 1 + 2 * qt) & 7) * 128;
      #pragma unroll
      for (int u = 0; u < 4; u++) {
        kreg[u] = *(const bf16x8*)(kbase + (size_t)(kv + kr[u]) * QKVN + kc[u]);
        vreg[u] = *(const f16x8*)(vbase + (size_t)vr[u] * N_ + kv + vc[u]);
      }
    }

    #pragma unroll
    for (int qs = 0; qs < 2; qs++) {
      // S^T = K @ Q^T   (Q already carries 0.125*log2e)
      f32x4 sv[2][8];
      #pragma unroll
      for (int i = 0; i < 2; i++)
        #pragma unroll
        for (int kf = 0; kf < 8; kf++) sv[i][kf] = fz;
      #pragma unroll
      for (int kk = 0; kk < 2; kk++) {
        #pragma unroll
        for (int kf = 0; kf < 8; kf++) {
          bf16x8 kb = *(const bf16x8*)(Ks + (kf * 16 + l16) * KSTR + kk * 32 + quad * 8);
          sv[0][kf] = __builtin_amdgcn_mfma_f32_16x16x32_bf16(kb, qf[qs][0][kk], sv[0][kf], 0, 0, 0);
          sv[1][kf] = __builtin_amdgcn_mfma_f32_16x16x32_bf16(kb, qf[qs][1][kk], sv[1][kf], 0, 0, 0);
        }
      }

      // softmax numerator, no max-subtract: p = exp2(s), packed cvt + f16 sums
      f16x4 pb[2][8];
      #pragma unroll
      for (int i = 0; i < 2; i++) {
        f16x2 rs2 = {(f16)0.f, (f16)0.f};
        #pragma unroll
        for (int kf = 0; kf < 8; kf++) {
          float p0 = fast_exp2(sv[i][kf][0]);
          float p1 = fast_exp2(sv[i][kf][1]);
          float p2 = fast_exp2(sv[i][kf][2]);
          float p3 = fast_exp2(sv[i][kf][3]);
          f16x2 h0 = cvt_pk_f16(p0, p1);
          f16x2 h1 = cvt_pk_f16(p2, p3);
          pb[i][kf] = __builtin_shufflevector(h0, h1, 0, 1, 2, 3);
          rs2 += h0;
          rs2 += h1;
        }
        float rs = (float)rs2[0] + (float)rs2[1];
        rs += __shfl_xor(rs, 16);
        rs += __shfl_xor(rs, 32);
        l_run[qs][i] += rs;
      }

      // O^T += V^T @ P^T, K=32 f16 MFMA: B = concat of two adjacent 16-key P
      // fragments; A = V^T read with the same slot->key permutation
      #pragma unroll
      for (int kb2 = 0; kb2 < 4; kb2++) {
        f16x8 pb32_0 = __builtin_shufflevector(pb[0][2 * kb2], pb[0][2 * kb2 + 1],
                                               0, 1, 2, 3, 4, 5, 6, 7);
        f16x8 pb32_1 = __builtin_shufflevector(pb[1][2 * kb2], pb[1][2 * kb2 + 1],
                                               0, 1, 2, 3, 4, 5, 6, 7);
        #pragma unroll
        for (int jd = 0; jd < 4; jd++) {
          const f16* vp = Vs + (jd * 16 + l16) * VSTR + kb2 * 32 + quad * 4;
          f16x4 v0 = *(const f16x4*)(vp);
          f16x4 v1 = *(const f16x4*)(vp + 16);
          f16x8 va8 = __builtin_shufflevector(v0, v1, 0, 1, 2, 3, 4, 5, 6, 7);
          oacc[qs][0][jd] = __builtin_amdgcn_mfma_f32_16x16x32_f16(va8, pb32_0, oacc[qs][0][jd], 0, 0, 0);
          oacc[qs][1][jd] = __builtin_amdgcn_mfma_f32_16x16x32_f16(va8, pb32_1, oacc[qs][1][jd], 0, 0, 0);
        }
      }
    }
  }

  // finalize: O = O^T / l (via v_rcp), 4B packed fp8 stores
  #pragma unroll
  for (int qs = 0; qs < 2; qs++)
    #pragma unroll
    for (int i = 0; i < 2; i++) {
      float inv = fast_rcp(l_run[qs][i]);
      int n = q0 + qs * 128 + wave * 32 + i * 16 + l16;
      #pragma unroll
      for (int jd = 0; jd < 4; jd++) {
        int p = to_fp8x4(oacc[qs][i][jd][0] * inv, oacc[qs][i][jd][1] * inv,
                         oacc[qs][i][jd][2] * inv, oacc[qs][i][jd][3] * inv);
        *(int*)(o + (size_t)(b * N_ + n) * C_ + h * HD_ + jd * 16 + quad * 4) = p;
      }
    }
}

// ---------------- host: workspace layout + launch ----------------
#define WQKVT_OFF  0u
#define WPROJT_OFF 1769472u
#define WFC1T_OFF  2359296u
#define WFC2T_OFF  4718592u
#define Y_OFF      7077888u
#define QKV_OFF    19660800u    // bf16 qkv (75.5 MB); aliased by fp8 hbuf (50.3 MB) after attn
#define VT_OFF     95158272u
#define O_OFF      120324096u
#define X1_OFF     132907008u
#define WS_NEEDED  183238656u

extern "C" void kernel_launch(void* const* d_in, const int* in_sizes, int n_in,
                              void* d_out, int out_size, void* d_ws, size_t ws_size,
                              hipStream_t stream) {
  if (ws_size < (size_t)WS_NEEDED) return;

  const float* x      = (const float*)d_in[0];
  const float* w_qkv  = (const float*)d_in[1];
  const float* w_proj = (const float*)d_in[2];
  const float* b_proj = (const float*)d_in[3];
  const float* ln1_g  = (const float*)d_in[4];
  const float* ln1_b  = (const float*)d_in[5];
  const float* ln2_g  = (const float*)d_in[6];
  const float* ln2_b  = (const float*)d_in[7];
  const float* ls1_g  = (const float*)d_in[8];
  const float* ls2_g  = (const float*)d_in[9];
  const float* w_fc1  = (const float*)d_in[10];
  const float* b_fc1  = (const float*)d_in[11];
  const float* w_fc2  = (const float*)d_in[12];
  const float* b_fc2  = (const float*)d_in[13];

  char* ws = (char*)d_ws;
  u8*    wqkvT  = (u8*)(ws + WQKVT_OFF);
  u8*    wprojT = (u8*)(ws + WPROJT_OFF);
  u8*    wfc1T  = (u8*)(ws + WFC1T_OFF);
  u8*    wfc2T  = (u8*)(ws + WFC2T_OFF);
  u8*    y      = (u8*)(ws + Y_OFF);
  bf16*  qkv    = (bf16*)(ws + QKV_OFF);
  u8*    hbuf   = (u8*)(ws + QKV_OFF);   // alias: qkv dead after attention
  f16*   vt     = (f16*)(ws + VT_OFF);
  u8*    o      = (u8*)(ws + O_OFF);
  float* x1     = (float*)(ws + X1_OFF);
  float* out    = (float*)d_out;

  // fused: 4 weight transposes + LN1
  prep_kernel<<<T_ALL + M_, 256, 0, stream>>>(
      x, w_qkv, w_proj, w_fc1, w_fc2, ln1_g, ln1_b,
      wqkvT, wprojT, wfc1T, wfc2T, y);

  // qkv: M=16384, N=2304, K=768 — 64 x 9 tiles of 256x256; fused V transpose -> vt
  gemm_bt<0, 256><<<(M_ / 256) * (QKVN / 256), 512, 0, stream>>>(
      y, wqkvT, qkv, nullptr, nullptr, nullptr, vt, M_, QKVN, C_, QKVN / 256);

  attn_kernel<<<(N_ / 256) * B_ * H_, 256, 0, stream>>>(qkv, vt, o);

  // proj: N=768 — 64 x 6 tiles of 256x128
  gemm_bt<1, 128><<<(M_ / 256) * (C_ / 128), 512, 0, stream>>>(
      o, wprojT, x1, b_proj, ls1_g, x, nullptr, M_, C_, C_, C_ / 128);

  ln_cast_kernel<<<M_, 256, 0, stream>>>(x1, ln2_g, ln2_b, y);

  // fc1: N=3072 — 64 x 12 tiles of 256x256
  gemm_bt<2, 256><<<(M_ / 256) * (MLP_ / 256), 512, 0, stream>>>(
      y, wfc1T, hbuf, b_fc1, nullptr, nullptr, nullptr, M_, MLP_, C_, MLP_ / 256);

  // fc2: N=768, K=3072 — 64 x 6 tiles of 256x128
  gemm_bt<3, 128><<<(M_ / 256) * (C_ / 128), 512, 0, stream>>>(
      hbuf, wfc2T, out, b_fc2, ls2_g, x1, nullptr, M_, C_, MLP_, C_ / 128);
}

// Round 8
// 446.065 us; speedup vs baseline: 1.4681x; 1.4681x over previous
//
#include <hip/hip_runtime.h>
#include <cstdint>
#include <cstddef>

// ---------------- types ----------------
typedef __bf16 bf16;
typedef __bf16 bf16x4 __attribute__((ext_vector_type(4)));
typedef __bf16 bf16x8 __attribute__((ext_vector_type(8)));
typedef _Float16 f16;
typedef _Float16 f16x2 __attribute__((ext_vector_type(2)));
typedef _Float16 f16x4 __attribute__((ext_vector_type(4)));
typedef _Float16 f16x8 __attribute__((ext_vector_type(8)));
typedef float  f32x4  __attribute__((ext_vector_type(4)));
typedef float  f32x16 __attribute__((ext_vector_type(16)));
typedef int    i32x4  __attribute__((ext_vector_type(4)));
typedef int    i32x8  __attribute__((ext_vector_type(8)));
typedef unsigned char u8;

#define B_   16
#define N_   1024
#define C_   768
#define H_   12
#define HD_  64
#define M_   (B_*N_)      // 16384 rows
#define MLP_ 3072
#define QKVN 2304         // 3*C
#define WSCALE 64.0f      // weights cast to fp8 at x64 (0.02-scale weights are subnormal in e4m3)
#define WINV  (1.0f/64.0f)
#define CEXP_ 0.18033688f // 0.125 * log2(e) — folded into Q at the qkv-GEMM epilogue

__device__ __forceinline__ void gll16(const void* g, void* l) {
  __builtin_amdgcn_global_load_lds((const __attribute__((address_space(1))) void*)g,
                                   (__attribute__((address_space(3))) void*)l,
                                   16, 0, 0);
}

template <int N>
__device__ __forceinline__ void wait_vm() {
  if constexpr (N == 0)      asm volatile("s_waitcnt vmcnt(0)" ::: "memory");
  else if constexpr (N == 3) asm volatile("s_waitcnt vmcnt(3)" ::: "memory");
  else                       asm volatile("s_waitcnt vmcnt(4)" ::: "memory");
}

// native v_exp_f32 / v_rcp_f32 — libm forms lower to slow OCML sequences
__device__ __forceinline__ float fast_exp2(float x) { return __builtin_amdgcn_exp2f(x); }
__device__ __forceinline__ float fast_rcp(float x)  { return __builtin_amdgcn_rcpf(x); }

// packed f32x2 -> f16x2 (v_cvt_pkrtz_f16_f32); builtin returns __fp16 vector on
// this ROCm -> bit_cast to our _Float16 vector type
__device__ __forceinline__ f16x2 cvt_pk_f16(float a, float b) {
  return __builtin_bit_cast(f16x2, __builtin_amdgcn_cvt_pkrtz(a, b));
}

// fp8 e4m3 (OCP on gfx950) converts via HW packed cvt
__device__ __forceinline__ u8 to_fp8(float a) {
  return (u8)(__builtin_amdgcn_cvt_pk_fp8_f32(a, a, 0, false) & 0xff);
}
__device__ __forceinline__ int to_fp8x4(float v0, float v1, float v2, float v3) {
  int p = __builtin_amdgcn_cvt_pk_fp8_f32(v0, v1, 0, false);
  p = __builtin_amdgcn_cvt_pk_fp8_f32(v2, v3, p, true);
  return p;  // bytes [v0,v1,v2,v3]
}

// ---------------- fused prep: 4 weight transposes + LN1, one launch ----------------
// transpose tiles: qkv 72x24=1728 | proj 24x24=576 | fc1 96x24=2304 | fc2 24x96=2304
#define T_QKV  1728
#define T_PROJ 2304   // cumulative
#define T_FC1  4608
#define T_FC2  6912
#define T_ALL  6912

__device__ __forceinline__ void tc_tile(const float* __restrict__ w, u8* __restrict__ wt,
                                        int K, int N, int t, int tid) {
  __shared__ float tile[32][33];
  int tiles_n = N >> 5;
  int n0 = (t % tiles_n) * 32, k0 = (t / tiles_n) * 32;
  int tx = tid & 31, ty = tid >> 5;   // (32,8)
  #pragma unroll
  for (int i = 0; i < 32; i += 8)
    tile[ty + i][tx] = w[(size_t)(k0 + ty + i) * N + n0 + tx];
  __syncthreads();
  #pragma unroll
  for (int i = 0; i < 32; i += 8)
    wt[(size_t)(n0 + ty + i) * K + k0 + tx] = to_fp8(tile[tx][ty + i] * WSCALE);
}

__global__ __launch_bounds__(256)
void prep_kernel(const float* __restrict__ x,
                 const float* __restrict__ w_qkv, const float* __restrict__ w_proj,
                 const float* __restrict__ w_fc1, const float* __restrict__ w_fc2,
                 const float* __restrict__ g, const float* __restrict__ bta,
                 u8* __restrict__ wqkvT, u8* __restrict__ wprojT,
                 u8* __restrict__ wfc1T, u8* __restrict__ wfc2T,
                 u8* __restrict__ y) {
  int bid = blockIdx.x, tid = threadIdx.x;
  if (bid < T_ALL) {
    if (bid < T_QKV)       tc_tile(w_qkv,  wqkvT,  C_,   QKVN, bid,          tid);
    else if (bid < T_PROJ) tc_tile(w_proj, wprojT, C_,   C_,   bid - T_QKV,  tid);
    else if (bid < T_FC1)  tc_tile(w_fc1,  wfc1T,  C_,   MLP_, bid - T_PROJ, tid);
    else                   tc_tile(w_fc2,  wfc2T,  MLP_, C_,   bid - T_FC1,  tid);
    return;
  }
  // LayerNorm row
  int row = bid - T_ALL;
  const float* xr = x + (size_t)row * C_;
  float v0 = xr[tid], v1 = xr[tid + 256], v2 = xr[tid + 512];
  float s  = v0 + v1 + v2;
  float sq = v0 * v0 + v1 * v1 + v2 * v2;
  #pragma unroll
  for (int off = 32; off > 0; off >>= 1) {
    s  += __shfl_xor(s,  off);
    sq += __shfl_xor(sq, off);
  }
  __shared__ float red[8];
  int wave = tid >> 6, lane = tid & 63;
  if (lane == 0) { red[wave] = s; red[4 + wave] = sq; }
  __syncthreads();
  s  = red[0] + red[1] + red[2] + red[3];
  sq = red[4] + red[5] + red[6] + red[7];
  float mean = s * (1.0f / C_);
  float var  = sq * (1.0f / C_) - mean * mean;
  float rstd = rsqrtf(var + 1e-5f);
  u8* yr = y + (size_t)row * C_;
  yr[tid]       = to_fp8((v0 - mean) * rstd * g[tid]       + bta[tid]);
  yr[tid + 256] = to_fp8((v1 - mean) * rstd * g[tid + 256] + bta[tid + 256]);
  yr[tid + 512] = to_fp8((v2 - mean) * rstd * g[tid + 512] + bta[tid + 512]);
}

// ---------------- LayerNorm (768) + cast to fp8 (LN2) ----------------
__global__ __launch_bounds__(256)
void ln_cast_kernel(const float* __restrict__ x, const float* __restrict__ g,
                    const float* __restrict__ bta, u8* __restrict__ y) {
  int row = blockIdx.x;
  int tid = threadIdx.x;
  const float* xr = x + (size_t)row * C_;
  float v0 = xr[tid], v1 = xr[tid + 256], v2 = xr[tid + 512];
  float s  = v0 + v1 + v2;
  float sq = v0 * v0 + v1 * v1 + v2 * v2;
  #pragma unroll
  for (int off = 32; off > 0; off >>= 1) {
    s  += __shfl_xor(s,  off);
    sq += __shfl_xor(sq, off);
  }
  __shared__ float red[8];
  int wave = tid >> 6, lane = tid & 63;
  if (lane == 0) { red[wave] = s; red[4 + wave] = sq; }
  __syncthreads();
  s  = red[0] + red[1] + red[2] + red[3];
  sq = red[4] + red[5] + red[6] + red[7];
  float mean = s * (1.0f / C_);
  float var  = sq * (1.0f / C_) - mean * mean;
  float rstd = rsqrtf(var + 1e-5f);
  u8* yr = y + (size_t)row * C_;
  yr[tid]       = to_fp8((v0 - mean) * rstd * g[tid]       + bta[tid]);
  yr[tid + 256] = to_fp8((v1 - mean) * rstd * g[tid + 256] + bta[tid + 256]);
  yr[tid + 512] = to_fp8((v2 - mean) * rstd * g[tid + 512] + bta[tid + 512]);
}

// ---------------- fp8 GEMM: C[M,N] = A[M,K] @ Bt[N,K]^T, fp32 acc, result x(1/64) ----------
// R12 pipeline: 256-row tile, 8 waves (512 thr), 3 LDS buffers, prefetch depth 2,
// counted vmcnt (never 0 in steady state) + raw s_barrier. MX-scaled 32x32x64
// f8f6f4 with unit e8m0 scales. EPI==0 folds CEXP into Q columns (col < 768).
// R13 (kept): EPI==0 writes the V columns (col >= 1536) transposed to vt[bh][d][n]
// as f16 (packed f16x4 over 4 consecutive rows) — replaces the transpose_v kernel.
template <int EPI, int BN_>
__global__ __launch_bounds__(512, 2)
void gemm_bt(const u8* __restrict__ A, const u8* __restrict__ Bt,
             void* __restrict__ outp, const float* __restrict__ bias,
             const float* __restrict__ ls, const float* __restrict__ resid,
             f16* __restrict__ vt_out,
             int M, int N, int K, int nb) {
  constexpr int BM = 256, BK = 64;
  constexpr int NJ  = BN_ / 128;     // 32-col blocks per wave (2 or 1)
  constexpr int NBL = BN_ / 128;     // B-staging loads per thread per tile
  constexpr int TL  = 2 + NBL;       // total loads per thread per tile (4 or 3)
  __shared__ __align__(16) u8 As[3][BM * BK];    // 3 x 16 KB
  __shared__ __align__(16) u8 Bs[3][BN_ * BK];   // 3 x 16/8 KB
  int tid  = threadIdx.x;
  int lane = tid & 63, wave = tid >> 6;
  int h32 = lane >> 5, r5 = lane & 31;
  int bid = blockIdx.x;
  int xcd = bid & 7, seq = bid >> 3;
  int mi = xcd + 8 * (seq / nb), ni = seq % nb;
  int m0 = mi * BM, n0 = ni * BN_;
  int wm = (wave >> 2) * 128, wn = (wave & 3) * (BN_ / 4);

  int iters = K >> 6;                 // K / BK
  int skew  = (ni * iters) / nb;      // < iters

  // staging source pointers, granule-swizzled at the global side
  const u8* ag[2]; const u8* bg[NBL];
  #pragma unroll
  for (int s = 0; s < 2; s++) {
    int u = tid + s * 512;
    int r = u >> 2, g = (u & 3) ^ ((r >> 1) & 3);
    ag[s] = A + (size_t)(m0 + r) * K + g * 16;
  }
  #pragma unroll
  for (int s = 0; s < NBL; s++) {
    int u = tid + s * 512;
    int r = u >> 2, g = (u & 3) ^ ((r >> 1) & 3);
    bg[s] = Bt + (size_t)(n0 + r) * K + g * 16;
  }
  // fragment-read swizzled granule offsets (bits 1..2 of LDS row == bits 1..2 of r5)
  int sw  = (r5 >> 1) & 3;
  int go0 = ((2 * h32 + 0) ^ sw) * 16;   // true k-chunk 32*h32 + [0,16)
  int go1 = ((2 * h32 + 1) ^ sw) * 16;   // true k-chunk 32*h32 + [16,32)

  f32x16 acc[4][NJ];
  #pragma unroll
  for (int i = 0; i < 4; i++)
    #pragma unroll
    for (int j = 0; j < NJ; j++)
      #pragma unroll
      for (int rg = 0; rg < 16; rg++) acc[i][j][rg] = 0.f;

  // prologue: issue tiles k(0)->buf0, k(1)->buf1; wait only for k(0)
  int k0 = skew;
  int k1 = (skew + 1 == iters) ? 0 : skew + 1;
  {
    int kn = k0 * BK;
    gll16(ag[0] + kn, &As[0][0] + tid * 16);
    gll16(ag[1] + kn, &As[0][0] + 8192 + tid * 16);
    gll16(bg[0] + kn, &Bs[0][0] + tid * 16);
    if constexpr (NBL == 2) gll16(bg[1] + kn, &Bs[0][0] + 8192 + tid * 16);
    kn = k1 * BK;
    gll16(ag[0] + kn, &As[1][0] + tid * 16);
    gll16(ag[1] + kn, &As[1][0] + 8192 + tid * 16);
    gll16(bg[0] + kn, &Bs[1][0] + tid * 16);
    if constexpr (NBL == 2) gll16(bg[1] + kn, &Bs[1][0] + 8192 + tid * 16);
  }
  wait_vm<TL>();
  __builtin_amdgcn_s_barrier();
  int kiss = (k1 + 1 == iters) ? 0 : k1 + 1;   // next tile index to issue

  int buf_c = 0;
  for (int t = 0; t < iters; t++) {
    if (t + 2 < iters) {   // issue tile t+2 into buf (t+2)%3 (free since barrier t-1)
      int bi = (buf_c == 0) ? 2 : buf_c - 1;
      int kn = kiss * BK;
      gll16(ag[0] + kn, &As[bi][0] + tid * 16);
      gll16(ag[1] + kn, &As[bi][0] + 8192 + tid * 16);
      gll16(bg[0] + kn, &Bs[bi][0] + tid * 16);
      if constexpr (NBL == 2) gll16(bg[1] + kn, &Bs[bi][0] + 8192 + tid * 16);
      kiss = (kiss + 1 == iters) ? 0 : kiss + 1;
    }
    // LDS -> reg fragments: one 32-byte (2x b128) read per 32-row frag, per operand
    i32x8 af[4], bfr[NJ];
    #pragma unroll
    for (int i = 0; i < 4; i++) {
      const u8* pa = &As[buf_c][0] + (wm + i * 32 + r5) * 64;
      i32x4 lo = *(const i32x4*)(pa + go0);
      i32x4 hi = *(const i32x4*)(pa + go1);
      af[i] = __builtin_shufflevector(lo, hi, 0, 1, 2, 3, 4, 5, 6, 7);
    }
    #pragma unroll
    for (int j = 0; j < NJ; j++) {
      const u8* pb = &Bs[buf_c][0] + (wn + j * 32 + r5) * 64;
      i32x4 lo = *(const i32x4*)(pb + go0);
      i32x4 hi = *(const i32x4*)(pb + go1);
      bfr[j] = __builtin_shufflevector(lo, hi, 0, 1, 2, 3, 4, 5, 6, 7);
    }
    // MX-scaled fp8 MFMA, scales = e8m0 0x7f = 2^0 (exact 1.0)
    __builtin_amdgcn_s_setprio(1);
    #pragma unroll
    for (int i = 0; i < 4; i++)
      #pragma unroll
      for (int j = 0; j < NJ; j++)
        acc[i][j] = __builtin_amdgcn_mfma_scale_f32_32x32x64_f8f6f4(
            af[i], bfr[j], acc[i][j], 0, 0, 0, 0x7f7f7f7f, 0, 0x7f7f7f7f);
    __builtin_amdgcn_s_setprio(0);
    if (t + 1 < iters) {
      if (t + 2 < iters) wait_vm<TL>();   // tile t+1 landed; t+2 stays in flight
      else               wait_vm<0>();    // tail drain
      __builtin_amdgcn_s_barrier();
    }
    buf_c = (buf_c == 2) ? 0 : buf_c + 1;
  }

  // epilogue: 32x32 C/D map — col = lane&31, row = (reg&3) + 8*(reg>>2) + 4*(lane>>5)
  #pragma unroll
  for (int i = 0; i < 4; i++) {
    int rowb = m0 + wm + i * 32 + h32 * 4;
    #pragma unroll
    for (int j = 0; j < NJ; j++) {
      int col = n0 + wn + j * 32 + r5;
      float bias_c = (EPI == 0) ? 0.f : bias[col];
      float ls_c   = (EPI == 1 || EPI == 3) ? ls[col] : 0.f;
      float gz_v = -2.45546696f * WINV;
      float gz_b = -2.45546696f * bias_c;
      if constexpr (EPI == 0) {
        float sc0 = (col < C_) ? (WINV * CEXP_) : WINV;
        bool isv = (n0 + wn + j * 32) >= 2 * C_;   // wave-uniform (32-col blocks)
        #pragma unroll
        for (int g = 0; g < 4; g++) {
          f16x4 vv;
          #pragma unroll
          for (int rr = 0; rr < 4; rr++) {
            float v = acc[i][j][4 * g + rr];
            int row = rowb + rr + 8 * g;
            ((bf16*)outp)[(size_t)row * N + col] = (bf16)(v * sc0);
            vv[rr] = (f16)(v * WINV);
          }
          if (isv) {   // fused V transpose: vt[bh][d][n], 4 consecutive n packed
            int row0 = rowb + 8 * g;
            int bb = row0 >> 10, nn = row0 & 1023;
            int hh = (col - 2 * C_) >> 6, dd = (col - 2 * C_) & 63;
            *(f16x4*)(vt_out + ((size_t)(bb * H_ + hh) * HD_ + dd) * N_ + nn) = vv;
          }
        }
      } else {
        #pragma unroll
        for (int rg = 0; rg < 16; rg++) {
          float v = acc[i][j][rg];
          int row = rowb + (rg & 3) + 8 * (rg >> 2);
          size_t idx = (size_t)row * N + col;
          if constexpr (EPI == 1) {
            float t = fmaf(v, WINV, bias_c);
            ((float*)outp)[idx] = fmaf(t, ls_c, resid[idx]);
          } else if constexpr (EPI == 2) {
            float t  = fmaf(v, WINV, bias_c);
            float zn = fmaf(v, gz_v, gz_b);
            float gv = t * fast_rcp(1.0f + fast_exp2(zn));   // t * sigmoid(1.702 t)
            ((u8*)outp)[idx] = to_fp8(gv);
          } else {
            float t = fmaf(v, WINV, bias_c);
            ((float*)outp)[idx] = fmaf(t, ls_c, resid[idx]);
          }
        }
      }
    }
  }
}

// ---------------- flash attention, S^T formulation ----------------
// REVERTED to the proven R11/R12 structure (measured 87.5 µs, 112 VGPR, no spill):
// 1-D grid 1536, XCD remap: bh = (bid&7) + 8*(seq>>3), q-tile = seq&7.
// R13's q-fusion (256 q-rows/block under launch_bounds(256,3)) spilled oacc to
// scratch (VGPR 84, WRITE_SIZE 620 MB, 3.7x slower) — reverted.
// R10: no-max softmax (scores bounded; shift-invariant; fp8 downstream).
// R11: PV via K=32 f16 MFMA with slot-consistent key permutation.
__global__ __launch_bounds__(256)
void attn_kernel(const bf16* __restrict__ qkv, const f16* __restrict__ vt,
                 u8* __restrict__ o) {
  constexpr int KSTR = 72;    // K tile stride (64 + 8 pad), bf16
  constexpr int VSTR = 136;   // V^T tile stride (128 + 8 pad), f16
  __shared__ __align__(16) bf16 Ks[128 * KSTR];   // 18432 B
  __shared__ __align__(16) f16  Vs[HD_ * VSTR];   // 17408 B

  int tid = threadIdx.x, lane = tid & 63, wave = tid >> 6;
  int quad = lane >> 4, l16 = lane & 15;
  int bid = blockIdx.x;
  int xcd = bid & 7, seq = bid >> 3;
  int bh = xcd + 8 * (seq >> 3);
  int b = bh / H_, h = bh % H_;
  int qt = seq & 7;
  int q0 = qt * 128;

  bf16x8 qf[2][2];
  #pragma unroll
  for (int i = 0; i < 2; i++)
    #pragma unroll
    for (int kk = 0; kk < 2; kk++)
      qf[i][kk] = *(const bf16x8*)(qkv + (size_t)(b * N_ + q0 + wave * 32 + i * 16 + l16) * QKVN
                                   + h * HD_ + kk * 32 + quad * 8);

  const f32x4 fz = {0.f, 0.f, 0.f, 0.f};
  f32x4 oacc[2][4];            // O^T[d = quad*4+r][q = l16]
  float l_run[2];
  #pragma unroll
  for (int i = 0; i < 2; i++) {
    #pragma unroll
    for (int jd = 0; jd < 4; jd++) oacc[i][jd] = fz;
    l_run[i] = 0.f;
  }

  const bf16* kbase = qkv + (size_t)(b * N_) * QKVN + C_ + h * HD_;
  const f16*  vbase = vt + (size_t)bh * HD_ * N_;

  // per-thread staging coords
  int kr[4], kc[4], vr[4], vc[4];
  #pragma unroll
  for (int u = 0; u < 4; u++) {
    int L = tid + u * 256;
    kr[u] = L >> 3;  kc[u] = (L & 7) * 8;
    vr[u] = L >> 4;  vc[u] = (L & 15) * 8;
  }

  // prefetch first (skewed) tile into registers
  bf16x8 kreg[4]; f16x8 vreg[4];
  {
    int kv = qt * 128;   // skew start
    #pragma unroll
    for (int u = 0; u < 4; u++) {
      kreg[u] = *(const bf16x8*)(kbase + (size_t)(kv + kr[u]) * QKVN + kc[u]);
      vreg[u] = *(const f16x8*)(vbase + (size_t)vr[u] * N_ + kv + vc[u]);
    }
  }

  for (int t = 0; t < 8; t++) {
    __syncthreads();   // prior compute done reading LDS
    #pragma unroll
    for (int u = 0; u < 4; u++) {
      *(bf16x8*)(Ks + kr[u] * KSTR + kc[u]) = kreg[u];
      *(f16x8*)(Vs + vr[u] * VSTR + vc[u])  = vreg[u];
    }
    __syncthreads();

    // issue next (skewed) tile's loads; they complete during compute below
    if (t + 1 < 8) {
      int kv = ((t + 1 + qt) & 7) * 128;
      #pragma unroll
      for (int u = 0; u < 4; u++) {
        kreg[u] = *(const bf16x8*)(kbase + (size_t)(kv + kr[u]) * QKVN + kc[u]);
        vreg[u] = *(const f16x8*)(vbase + (size_t)vr[u] * N_ + kv + vc[u]);
      }
    }

    // S^T = K @ Q^T   (Q already carries 0.125*log2e)
    f32x4 sv[2][8];
    #pragma unroll
    for (int i = 0; i < 2; i++)
      #pragma unroll
      for (int kf = 0; kf < 8; kf++) sv[i][kf] = fz;
    #pragma unroll
    for (int kk = 0; kk < 2; kk++) {
      #pragma unroll
      for (int kf = 0; kf < 8; kf++) {
        bf16x8 kb = *(const bf16x8*)(Ks + (kf * 16 + l16) * KSTR + kk * 32 + quad * 8);
        sv[0][kf] = __builtin_amdgcn_mfma_f32_16x16x32_bf16(kb, qf[0][kk], sv[0][kf], 0, 0, 0);
        sv[1][kf] = __builtin_amdgcn_mfma_f32_16x16x32_bf16(kb, qf[1][kk], sv[1][kf], 0, 0, 0);
      }
    }

    // softmax numerator, no max-subtract: p = exp2(s), packed cvt + packed f16 sums
    f16x4 pb[2][8];
    #pragma unroll
    for (int i = 0; i < 2; i++) {
      f16x2 rs2 = {(f16)0.f, (f16)0.f};
      #pragma unroll
      for (int kf = 0; kf < 8; kf++) {
        float p0 = fast_exp2(sv[i][kf][0]);
        float p1 = fast_exp2(sv[i][kf][1]);
        float p2 = fast_exp2(sv[i][kf][2]);
        float p3 = fast_exp2(sv[i][kf][3]);
        f16x2 h0 = cvt_pk_f16(p0, p1);
        f16x2 h1 = cvt_pk_f16(p2, p3);
        pb[i][kf] = __builtin_shufflevector(h0, h1, 0, 1, 2, 3);
        rs2 += h0;
        rs2 += h1;
      }
      float rs = (float)rs2[0] + (float)rs2[1];
      rs += __shfl_xor(rs, 16);
      rs += __shfl_xor(rs, 32);
      l_run[i] += rs;
    }

    // O^T += V^T @ P^T, K=32 f16 MFMA: B = concat of two adjacent 16-key P
    // fragments; A = V^T read with the same slot->key permutation
    #pragma unroll
    for (int kb2 = 0; kb2 < 4; kb2++) {
      f16x8 pb32_0 = __builtin_shufflevector(pb[0][2 * kb2], pb[0][2 * kb2 + 1],
                                             0, 1, 2, 3, 4, 5, 6, 7);
      f16x8 pb32_1 = __builtin_shufflevector(pb[1][2 * kb2], pb[1][2 * kb2 + 1],
                                             0, 1, 2, 3, 4, 5, 6, 7);
      #pragma unroll
      for (int jd = 0; jd < 4; jd++) {
        const f16* vp = Vs + (jd * 16 + l16) * VSTR + kb2 * 32 + quad * 4;
        f16x4 v0 = *(const f16x4*)(vp);
        f16x4 v1 = *(const f16x4*)(vp + 16);
        f16x8 va8 = __builtin_shufflevector(v0, v1, 0, 1, 2, 3, 4, 5, 6, 7);
        oacc[0][jd] = __builtin_amdgcn_mfma_f32_16x16x32_f16(va8, pb32_0, oacc[0][jd], 0, 0, 0);
        oacc[1][jd] = __builtin_amdgcn_mfma_f32_16x16x32_f16(va8, pb32_1, oacc[1][jd], 0, 0, 0);
      }
    }
  }

  // finalize: O = O^T / l (via v_rcp), 4B packed fp8 stores
  #pragma unroll
  for (int i = 0; i < 2; i++) {
    float inv = fast_rcp(l_run[i]);
    int n = q0 + wave * 32 + i * 16 + l16;
    #pragma unroll
    for (int jd = 0; jd < 4; jd++) {
      int p = to_fp8x4(oacc[i][jd][0] * inv, oacc[i][jd][1] * inv,
                       oacc[i][jd][2] * inv, oacc[i][jd][3] * inv);
      *(int*)(o + (size_t)(b * N_ + n) * C_ + h * HD_ + jd * 16 + quad * 4) = p;
    }
  }
}

// ---------------- host: workspace layout + launch ----------------
#define WQKVT_OFF  0u
#define WPROJT_OFF 1769472u
#define WFC1T_OFF  2359296u
#define WFC2T_OFF  4718592u
#define Y_OFF      7077888u
#define QKV_OFF    19660800u    // bf16 qkv (75.5 MB); aliased by fp8 hbuf (50.3 MB) after attn
#define VT_OFF     95158272u
#define O_OFF      120324096u
#define X1_OFF     132907008u
#define WS_NEEDED  183238656u

extern "C" void kernel_launch(void* const* d_in, const int* in_sizes, int n_in,
                              void* d_out, int out_size, void* d_ws, size_t ws_size,
                              hipStream_t stream) {
  if (ws_size < (size_t)WS_NEEDED) return;

  const float* x      = (const float*)d_in[0];
  const float* w_qkv  = (const float*)d_in[1];
  const float* w_proj = (const float*)d_in[2];
  const float* b_proj = (const float*)d_in[3];
  const float* ln1_g  = (const float*)d_in[4];
  const float* ln1_b  = (const float*)d_in[5];
  const float* ln2_g  = (const float*)d_in[6];
  const float* ln2_b  = (const float*)d_in[7];
  const float* ls1_g  = (const float*)d_in[8];
  const float* ls2_g  = (const float*)d_in[9];
  const float* w_fc1  = (const float*)d_in[10];
  const float* b_fc1  = (const float*)d_in[11];
  const float* w_fc2  = (const float*)d_in[12];
  const float* b_fc2  = (const float*)d_in[13];

  char* ws = (char*)d_ws;
  u8*    wqkvT  = (u8*)(ws + WQKVT_OFF);
  u8*    wprojT = (u8*)(ws + WPROJT_OFF);
  u8*    wfc1T  = (u8*)(ws + WFC1T_OFF);
  u8*    wfc2T  = (u8*)(ws + WFC2T_OFF);
  u8*    y      = (u8*)(ws + Y_OFF);
  bf16*  qkv    = (bf16*)(ws + QKV_OFF);
  u8*    hbuf   = (u8*)(ws + QKV_OFF);   // alias: qkv dead after attention
  f16*   vt     = (f16*)(ws + VT_OFF);
  u8*    o      = (u8*)(ws + O_OFF);
  float* x1     = (float*)(ws + X1_OFF);
  float* out    = (float*)d_out;

  // fused: 4 weight transposes + LN1
  prep_kernel<<<T_ALL + M_, 256, 0, stream>>>(
      x, w_qkv, w_proj, w_fc1, w_fc2, ln1_g, ln1_b,
      wqkvT, wprojT, wfc1T, wfc2T, y);

  // qkv: M=16384, N=2304, K=768 — 64 x 9 tiles of 256x256; fused V transpose -> vt
  gemm_bt<0, 256><<<(M_ / 256) * (QKVN / 256), 512, 0, stream>>>(
      y, wqkvT, qkv, nullptr, nullptr, nullptr, vt, M_, QKVN, C_, QKVN / 256);

  attn_kernel<<<(N_ / 128) * B_ * H_, 256, 0, stream>>>(qkv, vt, o);

  // proj: N=768 — 64 x 6 tiles of 256x128
  gemm_bt<1, 128><<<(M_ / 256) * (C_ / 128), 512, 0, stream>>>(
      o, wprojT, x1, b_proj, ls1_g, x, nullptr, M_, C_, C_, C_ / 128);

  ln_cast_kernel<<<M_, 256, 0, stream>>>(x1, ln2_g, ln2_b, y);

  // fc1: N=3072 — 64 x 12 tiles of 256x256
  gemm_bt<2, 256><<<(M_ / 256) * (MLP_ / 256), 512, 0, stream>>>(
      y, wfc1T, hbuf, b_fc1, nullptr, nullptr, nullptr, M_, MLP_, C_, MLP_ / 256);

  // fc2: N=768, K=3072 — 64 x 6 tiles of 256x128
  gemm_bt<3, 128><<<(M_ / 256) * (C_ / 128), 512, 0, stream>>>(
      hbuf, wfc2T, out, b_fc2, ls2_g, x1, nullptr, M_, C_, MLP_, C_ / 128);
}